// Round 1
// 1325.412 us; speedup vs baseline: 1.4341x; 1.4341x over previous
//
#include <hip/hip_runtime.h>
#include <hip/hip_bf16.h>
#include <math.h>

#define C_   1024
#define P_   2304      // 48*48
#define S4   331776    // 24^4

typedef __attribute__((ext_vector_type(8))) short short8;
typedef __attribute__((ext_vector_type(4))) float f32x4;
typedef __attribute__((ext_vector_type(4))) unsigned int u32x4;

__device__ inline unsigned short f2bf(float v) {
  unsigned u = __builtin_bit_cast(unsigned, v);
  u += 0x7fffu + ((u >> 16) & 1u);          // RNE
  return (unsigned short)(u >> 16);
}
__device__ inline float bf2f(unsigned short h) {
  unsigned u = ((unsigned)h) << 16;
  return __builtin_bit_cast(float, u);
}

// async global->LDS DMA, 16B per lane; LDS dest = wave-uniform base + lane*16
__device__ inline void async16(const void* g, void* l) {
  __builtin_amdgcn_global_load_lds(
      (const __attribute__((address_space(1))) unsigned int*)g,
      (__attribute__((address_space(3))) unsigned int*)l, 16, 0, 0);
}

// ---------------- K1: transpose + bf16 hi/lo split + sumsq partials --------
__global__ __launch_bounds__(256) void k_prep(
    const float* __restrict__ fA, const float* __restrict__ fB,
    unsigned short* __restrict__ TAhi, unsigned short* __restrict__ TAlo,
    unsigned short* __restrict__ TBhi, unsigned short* __restrict__ TBlo,
    float* __restrict__ part) {
  __shared__ float ld[64 * 65];
  __shared__ float pslds[512];
  const int c0 = blockIdx.x * 64, p0 = blockIdx.y * 64;
  const int fb = blockIdx.z, f = fb >> 3, b = fb & 7;
  const float* src = (f ? fB : fA) + (size_t)b * C_ * P_;
  unsigned short* Thi = (f ? TBhi : TAhi) + (size_t)b * P_ * C_;
  unsigned short* Tlo = (f ? TBlo : TAlo) + (size_t)b * P_ * C_;
  const int t = threadIdx.x;
#pragma unroll
  for (int e = 0; e < 4; ++e) {
    int cid = t + e * 256;
    int r = cid >> 4, ch = cid & 15;
    float4 v = *(const float4*)&src[(size_t)(c0 + r) * P_ + p0 + ch * 4];
    ld[r * 65 + ch * 4 + 0] = v.x;
    ld[r * 65 + ch * 4 + 1] = v.y;
    ld[r * 65 + ch * 4 + 2] = v.z;
    ld[r * 65 + ch * 4 + 3] = v.w;
  }
  __syncthreads();
#pragma unroll
  for (int e = 0; e < 2; ++e) {
    int ocid = t + e * 256;
    int pl = ocid >> 3, c8 = ocid & 7;
    unsigned short hi[8], lo[8];
    float sq = 0.f;
#pragma unroll
    for (int s = 0; s < 8; ++s) {
      float v = ld[(c8 * 8 + s) * 65 + pl];
      unsigned short h = f2bf(v);
      float rem = v - bf2f(h);
      hi[s] = h; lo[s] = f2bf(rem);
      sq = fmaf(v, v, sq);
    }
    size_t go = (size_t)(p0 + pl) * C_ + c0 + c8 * 8;
    *(uint4*)&Thi[go] = *(uint4*)hi;
    *(uint4*)&Tlo[go] = *(uint4*)lo;
    pslds[ocid] = sq;
  }
  __syncthreads();
  if (t < 64) {
    float s = 0.f;
#pragma unroll
    for (int c8 = 0; c8 < 8; ++c8) s += pslds[t * 8 + c8];
    part[((size_t)fb * 16 + blockIdx.x) * P_ + p0 + t] = s;
  }
}

// ---------------- K2: finalize inverse norms -------------------------------
__global__ void k_invnorm(const float* __restrict__ part, float* __restrict__ inv) {
  int p = blockIdx.x * 256 + threadIdx.x;
  int fb = blockIdx.y;
  float s = 1e-6f;
  for (int ct = 0; ct < 16; ++ct) s += part[((size_t)fb * 16 + ct) * P_ + p];
  inv[(size_t)fb * P_ + p] = 1.0f / sqrtf(s);
}

// ---------------- K3: bf16x3 MFMA correlation + relu/norm/4D-maxpool -------
__global__ __launch_bounds__(256, 3) void k_corr_mfma(
    const unsigned short* __restrict__ TAhi_, const unsigned short* __restrict__ TAlo_,
    const unsigned short* __restrict__ TBhi_, const unsigned short* __restrict__ TBlo_,
    const float* __restrict__ invn, float* __restrict__ pooled) {
  __shared__ __align__(16) char lds_raw[37248];
  unsigned short* stage = (unsigned short*)lds_raw;
  float* epi = (float*)lds_raw;

  const int b = blockIdx.y;
  const size_t tb = (size_t)b * P_ * C_;
  const unsigned short* TAhi = TAhi_ + tb;
  const unsigned short* TAlo = TAlo_ + tb;
  const unsigned short* TBhi = TBhi_ + tb;
  const unsigned short* TBlo = TBlo_ + tb;
  float* out = pooled + (size_t)b * S4;

  const int g = blockIdx.x;
  const int xcd = g & 7, idx = g >> 3;
  const int ti = (xcd & 3) * 6 + idx % 6;
  const int tj = (xcd >> 2) * 12 + idx / 6;
  const int p0 = ti * 96, q0 = tj * 96;
  const int t = threadIdx.x;
  const int lane = t & 63, w = t >> 6;
  const int wr = w >> 1, wc = w & 1;
  const int m15 = lane & 15, q4 = lane >> 4;
  const int koff = q4 * 8;

  f32x4 acc[3][3];
#pragma unroll
  for (int a = 0; a < 3; ++a)
#pragma unroll
    for (int c = 0; c < 3; ++c) acc[a][c] = (f32x4){0.f, 0.f, 0.f, 0.f};

  const unsigned short* gld[8];
  int ldsb[8];
#pragma unroll
  for (int e = 0; e < 8; ++e) {
    int chunk = (w * 8 + e) * 64 + lane;
    int arr = chunk / 480;
    int rem = chunk - arr * 480;
    int row = rem / 5, kc = rem - row * 5;
    bool dum = (arr >= 4) || (kc == 4);
    if (arr >= 4) { arr = 0; row = 0; }
    const unsigned short* base = (arr == 0) ? TAhi : (arr == 1) ? TAlo
                               : (arr == 2) ? TBhi : TBlo;
    int pb = (arr < 2) ? p0 : q0;
    gld[e] = base + (size_t)(pb + row) * C_ + (dum ? 0 : kc * 8);
    ldsb[e] = (w * 8 + e) * 1024;
  }

  for (int kt = 0; kt < C_; kt += 32) {
    __syncthreads();
#pragma unroll
    for (int e = 0; e < 8; ++e)
      async16(gld[e] + kt, lds_raw + ldsb[e]);
    asm volatile("s_waitcnt vmcnt(0)" ::: "memory");
    __syncthreads();

    const unsigned short* Ah = stage;
    const unsigned short* Al = stage + 3840;
    const unsigned short* Bh = stage + 7680;
    const unsigned short* Bl = stage + 11520;
    short8 ah[3], al[3], bh[3], bl[3];
#pragma unroll
    for (int a = 0; a < 3; ++a) {
      int row = wr * 48 + a * 16 + m15;
      ah[a] = *(const short8*)&Ah[row * 40 + koff];
      al[a] = *(const short8*)&Al[row * 40 + koff];
    }
#pragma unroll
    for (int c = 0; c < 3; ++c) {
      int row = wc * 48 + c * 16 + m15;
      bh[c] = *(const short8*)&Bh[row * 40 + koff];
      bl[c] = *(const short8*)&Bl[row * 40 + koff];
    }
#pragma unroll
    for (int a = 0; a < 3; ++a)
#pragma unroll
      for (int c = 0; c < 3; ++c)
        acc[a][c] = __builtin_amdgcn_mfma_f32_16x16x32_bf16(ah[a], bh[c], acc[a][c], 0, 0, 0);
#pragma unroll
    for (int a = 0; a < 3; ++a)
#pragma unroll
      for (int c = 0; c < 3; ++c)
        acc[a][c] = __builtin_amdgcn_mfma_f32_16x16x32_bf16(ah[a], bl[c], acc[a][c], 0, 0, 0);
#pragma unroll
    for (int a = 0; a < 3; ++a)
#pragma unroll
      for (int c = 0; c < 3; ++c)
        acc[a][c] = __builtin_amdgcn_mfma_f32_16x16x32_bf16(al[a], bh[c], acc[a][c], 0, 0, 0);
  }
  __syncthreads();

  const float* invA = invn + (size_t)b * P_;
  const float* invB = invn + (size_t)(8 + b) * P_;
  float ib[3];
#pragma unroll
  for (int c = 0; c < 3; ++c) ib[c] = invB[q0 + wc * 48 + c * 16 + m15];
#pragma unroll
  for (int a = 0; a < 3; ++a) {
#pragma unroll
    for (int reg = 0; reg < 4; ++reg) {
      int pl = wr * 48 + a * 16 + q4 * 4 + reg;
      float ia = invA[p0 + pl];
#pragma unroll
      for (int c = 0; c < 3; ++c) {
        int ql = wc * 48 + c * 16 + m15;
        epi[pl * 97 + ql] = acc[a][c][reg] * ia * ib[c];
      }
    }
  }
  __syncthreads();

  for (int idx2 = t; idx2 < 576; idx2 += 256) {
    int j = idx2 / 24, l = idx2 % 24;
    float m = -1e30f;
#pragma unroll
    for (int dh = 0; dh < 2; ++dh)
#pragma unroll
      for (int dw = 0; dw < 2; ++dw) {
        int row = dh * 48 + 2 * j + dw;
#pragma unroll
        for (int d2 = 0; d2 < 2; ++d2)
#pragma unroll
          for (int dw2 = 0; dw2 < 2; ++dw2)
            m = fmaxf(m, epi[row * 97 + d2 * 48 + 2 * l + dw2]);
      }
    float r = fmaxf(m, 0.f);
    float v = r / sqrtf(r * r + 1e-6f);
    out[(size_t)(ti * 24 + j) * 576 + tj * 24 + l] = v;
  }
}

// ---------------- K4a: row max (over kl, per ij) ---------------------------
__global__ void k_rowmax(const float* __restrict__ x, float* __restrict__ amax) {
  int row = blockIdx.x;
  const float* r = x + (size_t)row * 576;
  float m = -1e30f;
  for (int e = threadIdx.x; e < 576; e += 64) m = fmaxf(m, r[e]);
  for (int off = 32; off > 0; off >>= 1) m = fmaxf(m, __shfl_down(m, off, 64));
  if (threadIdx.x == 0) amax[row] = m;
}

// ---------------- K4b: col max (over ij, per kl) ---------------------------
__global__ void k_colmax(const float* __restrict__ x, float* __restrict__ bmax) {
  __shared__ float pl[4][64];
  int b = blockIdx.x, klc = blockIdx.y * 64;
  int t = threadIdx.x;
  int kl = klc + (t & 63), seg = t >> 6;
  const float* xb = x + (size_t)b * S4;
  float m = -1e30f;
  for (int ij = seg * 144; ij < (seg + 1) * 144; ++ij)
    m = fmaxf(m, xb[(size_t)ij * 576 + kl]);
  pl[seg][t & 63] = m;
  __syncthreads();
  if (t < 64) {
    float r = fmaxf(fmaxf(pl[0][t], pl[1][t]), fmaxf(pl[2][t], pl[3][t]));
    bmax[b * 576 + klc + t] = r;
  }
}

// ---------------- K5: mutual matching elementwise --------------------------
__global__ void k_mm_apply(const float* __restrict__ x,
                           const float* __restrict__ amax,
                           const float* __restrict__ bmax,
                           float* __restrict__ y) {
  int i = blockIdx.x * 256 + threadIdx.x;
  int b = i / S4, r = i % S4;
  int ij = r / 576, kl = r % 576;
  float c = x[i];
  y[i] = c * (c / (amax[b * 576 + ij] + 1e-5f)) * (c / (bmax[b * 576 + kl] + 1e-5f));
}

// ---------------- K6: scalar 4D conv (kept for conv3 <10,1>) ---------------
template <int CIN, int COUT>
__global__ __launch_bounds__(192, 4) void k_conv4d(
    const float* __restrict__ x, size_t xbs,
    const float* __restrict__ w, const float* __restrict__ bias,
    float* __restrict__ y, size_t ybs) {
  __shared__ float tile[9 * 702];
  const float* xb = x + xbs * blockIdx.y;
  float* yb = y + ybs * blockIdx.y;
  const int ij = blockIdx.x;
  const int i = ij / 24, j = ij % 24;
  const int t = threadIdx.x;
  const int k = t >> 3;
  const int l0 = (t & 7) * 3;

  int soff[4]; bool eok[4], klok[4]; int eidx[4];
#pragma unroll
  for (int q = 0; q < 4; ++q) {
    int e = t + q * 192;
    eidx[q] = e; eok[q] = (e < 702);
    int row = e / 27, col = e % 27;
    klok[q] = (row >= 1 && row < 25 && col >= 1 && col < 25);
    soff[q] = (row - 1) * 24 + (col - 1);
  }

  float acc[COUT][3];
#pragma unroll
  for (int co = 0; co < COUT; ++co)
#pragma unroll
    for (int oo = 0; oo < 3; ++oo) acc[co][oo] = 0.f;

  for (int ci = 0; ci < CIN; ++ci) {
    __syncthreads();
#pragma unroll
    for (int pln = 0; pln < 9; ++pln) {
      int ii = i + pln / 3 - 1, jj = j + pln % 3 - 1;
      const bool slab_ok = (ii >= 0 && ii < 24 && jj >= 0 && jj < 24);
      const float* src = xb + (size_t)ci * S4 + (size_t)(ii * 24 + jj) * 576;
#pragma unroll
      for (int q = 0; q < 4; ++q) {
        if (eok[q]) {
          float v = 0.f;
          if (slab_ok && klok[q]) v = src[soff[q]];
          tile[pln * 702 + eidx[q]] = v;
        }
      }
    }
    __syncthreads();
#pragma unroll
    for (int pln = 0; pln < 9; ++pln) {
      const float* base = &tile[pln * 702 + k * 27 + l0];
#pragma unroll
      for (int dk = 0; dk < 3; ++dk) {
        float c0 = base[dk * 27 + 0], c1 = base[dk * 27 + 1],
              c2 = base[dk * 27 + 2], c3 = base[dk * 27 + 3],
              c4 = base[dk * 27 + 4];
#pragma unroll
        for (int co = 0; co < COUT; ++co) {
          const float* wr = w + ((size_t)co * CIN + ci) * 81 + pln * 9 + dk * 3;
          float w0 = wr[0], w1 = wr[1], w2 = wr[2];
          acc[co][0] = fmaf(w0, c0, acc[co][0]);
          acc[co][0] = fmaf(w1, c1, acc[co][0]);
          acc[co][0] = fmaf(w2, c2, acc[co][0]);
          acc[co][1] = fmaf(w0, c1, acc[co][1]);
          acc[co][1] = fmaf(w1, c2, acc[co][1]);
          acc[co][1] = fmaf(w2, c3, acc[co][1]);
          acc[co][2] = fmaf(w0, c2, acc[co][2]);
          acc[co][2] = fmaf(w1, c3, acc[co][2]);
          acc[co][2] = fmaf(w2, c4, acc[co][2]);
        }
      }
    }
  }
#pragma unroll
  for (int co = 0; co < COUT; ++co) {
    float bv = bias[co];
#pragma unroll
    for (int oo = 0; oo < 3; ++oo) {
      float v = fmaxf(acc[co][oo] + bv, 0.f);
      yb[(size_t)co * S4 + (size_t)ij * 576 + k * 24 + l0 + oo] = v;
    }
  }
}

// ---------------- K7: conv1 (CIN=1, COUT=10) -> packed halo layout ---------
// C1p[b][ij slab][pos 26*26][ci 10] dwords; pos=(k'+1)*26+(l'+1); value =
// (bf16_hi<<16)|bf16_lo of relu(conv1+b1). Halo rows/cols and pad [6760,6912)
// zeroed (pad IS read by conv2's K=32 window overrun -> must be finite).
__global__ __launch_bounds__(192, 4) void k_conv1_pack(
    const float* __restrict__ x, const float* __restrict__ w,
    const float* __restrict__ bias, unsigned int* __restrict__ C1p) {
  __shared__ float tile[9 * 702];
  const float* xb = x + (size_t)S4 * blockIdx.y;
  unsigned int* yb = C1p + ((size_t)blockIdx.y * 576 + blockIdx.x) * 6912;
  const int ij = blockIdx.x;
  const int i = ij / 24, j = ij % 24;
  const int t = threadIdx.x;
  const int k = t >> 3;
  const int l0 = (t & 7) * 3;

  if (t < 152) yb[6760 + t] = 0u;
  if (t < 100) {
    int kk, ll;
    if (t < 26)      { kk = 0;          ll = t; }
    else if (t < 52) { kk = 25;         ll = t - 26; }
    else if (t < 76) { kk = t - 52 + 1; ll = 0; }
    else             { kk = t - 76 + 1; ll = 25; }
    unsigned int* p = yb + (kk * 26 + ll) * 10;
#pragma unroll
    for (int q = 0; q < 10; ++q) p[q] = 0u;
  }

  int soff[4]; bool eok[4], klok[4]; int eidx[4];
#pragma unroll
  for (int q = 0; q < 4; ++q) {
    int e = t + q * 192;
    eidx[q] = e; eok[q] = (e < 702);
    int row = e / 27, col = e % 27;
    klok[q] = (row >= 1 && row < 25 && col >= 1 && col < 25);
    soff[q] = (row - 1) * 24 + (col - 1);
  }

  float acc[10][3];
#pragma unroll
  for (int co = 0; co < 10; ++co)
#pragma unroll
    for (int oo = 0; oo < 3; ++oo) acc[co][oo] = 0.f;

#pragma unroll
  for (int pln = 0; pln < 9; ++pln) {
    int ii = i + pln / 3 - 1, jj = j + pln % 3 - 1;
    const bool slab_ok = (ii >= 0 && ii < 24 && jj >= 0 && jj < 24);
    const float* src = xb + (size_t)(ii * 24 + jj) * 576;
#pragma unroll
    for (int q = 0; q < 4; ++q) {
      if (eok[q]) {
        float v = 0.f;
        if (slab_ok && klok[q]) v = src[soff[q]];
        tile[pln * 702 + eidx[q]] = v;
      }
    }
  }
  __syncthreads();
#pragma unroll
  for (int pln = 0; pln < 9; ++pln) {
    const float* base = &tile[pln * 702 + k * 27 + l0];
#pragma unroll
    for (int dk = 0; dk < 3; ++dk) {
      float c0 = base[dk * 27 + 0], c1 = base[dk * 27 + 1],
            c2 = base[dk * 27 + 2], c3 = base[dk * 27 + 3],
            c4 = base[dk * 27 + 4];
#pragma unroll
      for (int co = 0; co < 10; ++co) {
        const float* wr = w + (size_t)co * 81 + pln * 9 + dk * 3;
        float w0 = wr[0], w1 = wr[1], w2v = wr[2];
        acc[co][0] = fmaf(w0, c0, acc[co][0]);
        acc[co][0] = fmaf(w1, c1, acc[co][0]);
        acc[co][0] = fmaf(w2v, c2, acc[co][0]);
        acc[co][1] = fmaf(w0, c1, acc[co][1]);
        acc[co][1] = fmaf(w1, c2, acc[co][1]);
        acc[co][1] = fmaf(w2v, c3, acc[co][1]);
        acc[co][2] = fmaf(w0, c2, acc[co][2]);
        acc[co][2] = fmaf(w1, c3, acc[co][2]);
        acc[co][2] = fmaf(w2v, c4, acc[co][2]);
      }
    }
  }
#pragma unroll
  for (int oo = 0; oo < 3; ++oo) {
    unsigned int* baseo = yb + ((k + 1) * 26 + (l0 + oo + 1)) * 10;
#pragma unroll
    for (int co = 0; co < 10; ++co) {
      float v = fmaxf(acc[co][oo] + bias[co], 0.f);
      unsigned short hi = f2bf(v);
      unsigned short lo = f2bf(v - bf2f(hi));
      baseo[co] = ((unsigned)hi << 16) | (unsigned)lo;
    }
  }
}

// ---------------- K8: pack conv2 weights into B fragments ------------------
// Bh/Bl [30 taps][16 co][32 kappa]; kappa = dl*10+ci (30 used, 2 zero);
// taps 0..26 = (di,dj,dk), taps 27..29 = all-zero (for out-of-range slabs).
__global__ void k_packw2(const float* __restrict__ w2,
                         unsigned short* __restrict__ Bh,
                         unsigned short* __restrict__ Bl) {
  int idx = blockIdx.x * 256 + threadIdx.x;
  if (idx >= 15360) return;
  int tap = idx >> 9;
  int n = (idx >> 5) & 15;
  int kap = idx & 31;
  float v = 0.f;
  if (tap < 27 && n < 10 && kap < 30) {
    int ci = kap % 10, dl = kap / 10;
    v = w2[(size_t)(n * 10 + ci) * 81 + tap * 3 + dl];
  }
  unsigned short hi = f2bf(v);
  unsigned short lo = f2bf(v - bf2f(hi));
  Bh[idx] = hi; Bl[idx] = lo;
}

// ---------------- K9: conv2 (10->10) via MFMA, tap-decomposed GEMM ---------
// One block per (b, ij). M = 576 outputs (36 tiles of 16, 9/wave), N = 16
// (10 co), K = 32 window = 3 dl-shifts x 10 ci (contiguous dwords in C1p
// slab layout; kappa 30,31 hit zero weights). 9 slabs (di,dj), 3 dk taps
// each, bf16x3 emulation: AhBh + AhBl + AlBh.
// LDS: 2 x 28672B double buffer, filled by global_load_lds (28 groups of
// 1024B, 7 per wave). vmcnt contract: per-iter vmem issue order is
// [7 stage][6 B-frag loads]; wait leaves newest 6+7+6=19 outstanding so the
// next-slab DMA + next B frags stay in flight across the compute phase.
__global__ __launch_bounds__(256, 2) void k_conv2_mfma(
    const unsigned int* __restrict__ C1p,
    const unsigned short* __restrict__ Bh, const unsigned short* __restrict__ Bl,
    const float* __restrict__ bias, float* __restrict__ C2) {
  __shared__ __align__(16) unsigned int lds[2 * 7168];
  const int b = blockIdx.y, ij = blockIdx.x;
  const int i = ij / 24, j = ij % 24;
  const int t = threadIdx.x, lane = t & 63, w = t >> 6;
  const int m15 = lane & 15, q4 = lane >> 4;

  // per-lane A row bases for this wave's 9 M-tiles (center k'' = k+1, dk=0)
  int rowb[9];
#pragma unroll
  for (int mi = 0; mi < 9; ++mi) {
    int kl = (w * 9 + mi) * 16 + m15;
    int kk = kl / 24, ll = kl % 24;
    rowb[mi] = ((kk + 1) * 26 + ll) * 10;
  }

  auto slabinfo = [&](int s, const unsigned int*& sp, int& tb) {
    int d3 = s / 3;
    int di = d3 - 1, dj = s - d3 * 3 - 1;
    int ii = i + di, jj = j + dj;
    bool v = ((unsigned)ii < 24u) && ((unsigned)jj < 24u);
    sp = C1p + ((size_t)b * 576 + (size_t)(v ? (ii * 24 + jj) : ij)) * 6912;
    tb = v ? s * 3 : 27;   // invalid slab -> zero-weight taps 27..29
  };

  auto STAGE = [&](const unsigned int* sp, int par) {
#pragma unroll
    for (int r = 0; r < 7; ++r) {
      const int g = w * 7 + r;                         // 0..27
      const unsigned int* gp = sp + (g < 27 ? g * 256 : 0) + lane * 4;
      async16(gp, (char*)lds + par * 28672 + g * 1024);
    }
  };

  auto LOADB = [&](int tb, short8* h3, short8* l3) {
#pragma unroll
    for (int dk = 0; dk < 3; ++dk) {
      size_t o = (size_t)((tb + dk) * 16 + m15) * 32 + (size_t)q4 * 8;
      h3[dk] = *(const short8*)(Bh + o);
      l3[dk] = *(const short8*)(Bl + o);
    }
  };

  f32x4 acc[9];
#pragma unroll
  for (int mi = 0; mi < 9; ++mi) acc[mi] = (f32x4){0.f, 0.f, 0.f, 0.f};
  short8 bhc[3], blc[3], bhn[3], bln[3];

  {
    const unsigned int* sp; int tb;
    slabinfo(0, sp, tb);
    STAGE(sp, 0);
    LOADB(tb, bhc, blc);
  }

  for (int s = 0; s < 9; ++s) {
    const int par = s & 1;
    if (s < 8) {
      const unsigned int* sp; int tb;
      slabinfo(s + 1, sp, tb);
      STAGE(sp, par ^ 1);
      LOADB(tb, bhn, bln);
      asm volatile("s_waitcnt vmcnt(19)" ::: "memory");
    } else {
      asm volatile("s_waitcnt vmcnt(6)" ::: "memory");
    }
    __builtin_amdgcn_s_barrier();
    __builtin_amdgcn_sched_barrier(0);

    const unsigned int* buf = lds + par * 7168;
#pragma unroll
    for (int dk = 0; dk < 3; ++dk) {
#pragma unroll
      for (int mi = 0; mi < 9; ++mi) {
        const uint2* p = (const uint2*)(buf + (rowb[mi] + (dk - 1) * 260 + q4 * 8));
        uint2 d0 = p[0], d1 = p[1], d2 = p[2], d3 = p[3];
        u32x4 hd, lv;
        hd.x = __builtin_amdgcn_perm(d0.y, d0.x, 0x07060302u);
        hd.y = __builtin_amdgcn_perm(d1.y, d1.x, 0x07060302u);
        hd.z = __builtin_amdgcn_perm(d2.y, d2.x, 0x07060302u);
        hd.w = __builtin_amdgcn_perm(d3.y, d3.x, 0x07060302u);
        lv.x = __builtin_amdgcn_perm(d0.y, d0.x, 0x05040100u);
        lv.y = __builtin_amdgcn_perm(d1.y, d1.x, 0x05040100u);
        lv.z = __builtin_amdgcn_perm(d2.y, d2.x, 0x05040100u);
        lv.w = __builtin_amdgcn_perm(d3.y, d3.x, 0x05040100u);
        short8 ah = __builtin_bit_cast(short8, hd);
        short8 al = __builtin_bit_cast(short8, lv);
        acc[mi] = __builtin_amdgcn_mfma_f32_16x16x32_bf16(ah, bhc[dk], acc[mi], 0, 0, 0);
        acc[mi] = __builtin_amdgcn_mfma_f32_16x16x32_bf16(ah, blc[dk], acc[mi], 0, 0, 0);
        acc[mi] = __builtin_amdgcn_mfma_f32_16x16x32_bf16(al, bhc[dk], acc[mi], 0, 0, 0);
      }
    }
    __builtin_amdgcn_sched_barrier(0);
    __builtin_amdgcn_s_barrier();
#pragma unroll
    for (int dk = 0; dk < 3; ++dk) { bhc[dk] = bhn[dk]; blc[dk] = bln[dk]; }
  }

  if (m15 < 10) {
    const float bv = bias[m15];
    float* outp = C2 + ((size_t)b * 10 + m15) * S4 + (size_t)ij * 576;
#pragma unroll
    for (int mi = 0; mi < 9; ++mi) {
#pragma unroll
      for (int reg = 0; reg < 4; ++reg) {
        int kl = (w * 9 + mi) * 16 + q4 * 4 + reg;
        outp[kl] = fmaxf(acc[mi][reg] + bv, 0.f);
      }
    }
  }
}

// ---------------------------------------------------------------------------
extern "C" void kernel_launch(void* const* d_in, const int* in_sizes, int n_in,
                              void* d_out, int out_size, void* d_ws, size_t ws_size,
                              hipStream_t stream) {
  const float* fA = (const float*)d_in[0];
  const float* fB = (const float*)d_in[1];
  const float* w1 = (const float*)d_in[2];
  const float* b1 = (const float*)d_in[3];
  const float* w2 = (const float*)d_in[4];
  const float* b2 = (const float*)d_in[5];
  const float* w3 = (const float*)d_in[6];
  const float* b3 = (const float*)d_in[7];
  float* out = (float*)d_out;
  float* ws = (float*)d_ws;
  (void)in_sizes; (void)n_in; (void)out_size; (void)ws_size;

  // --- workspace layout (floats/dwords), total 58,407,936 fl = 233.6 MB ---
  // lifetimes: T arrays (steps 1-3) / C1p (5-6) / C2 (6-7) overlay region X;
  // pooled/part/invn/amax1/bmax1 live in [37.75M,41.04M) (dead before C2
  // write); C3/amax2/bmax2 in [0,2.67M) (C1p dead when conv3 runs).
  unsigned int* C1p  = (unsigned int*)ws;            // 31,850,496 dw (8*576*6912)
  float* C2          = ws + 31850496;                // 26,542,080 fl
  unsigned short* TAhi = (unsigned short*)ws;        // 4 x 18,874,368 shorts
  unsigned short* TAlo = TAhi + (size_t)8 * P_ * C_;
  unsigned short* TBhi = TAlo + (size_t)8 * P_ * C_;
  unsigned short* TBlo = TBhi + (size_t)8 * P_ * C_; // ends at fl 37,748,736
  float* pooled = ws + 37748736;                     // 2,654,208
  float* part   = ws + 40402944;                     // 589,824
  float* invn   = ws + 40992768;                     // 36,864
  float* amax1  = ws + 41029632;                     // 4,608
  float* bmax1  = ws + 41034240;                     // 4,608
  float* C3     = ws + 0;                            // 2,654,208 (over dead C1p)
  float* amax2  = ws + 2654208;
  float* bmax2  = ws + 2658816;
  unsigned short* Bh = (unsigned short*)(ws + 58392576);  // 15,360 shorts
  unsigned short* Bl = Bh + 15360;                        // 15,360 shorts

  // 1+2) transpose/split + norms + MFMA correlation
  k_prep<<<dim3(16, 36, 16), 256, 0, stream>>>(fA, fB, TAhi, TAlo, TBhi, TBlo, part);
  k_invnorm<<<dim3(9, 16), 256, 0, stream>>>(part, invn);
  k_corr_mfma<<<dim3(576, 8), 256, 0, stream>>>(TAhi, TAlo, TBhi, TBlo, invn, pooled);

  // 3) mutual matching #1 (in place)
  k_rowmax<<<dim3(8 * 576), 64, 0, stream>>>(pooled, amax1);
  k_colmax<<<dim3(8, 9), 256, 0, stream>>>(pooled, bmax1);
  k_mm_apply<<<dim3(10368), 256, 0, stream>>>(pooled, amax1, bmax1, pooled);

  // 4) neighbourhood consensus: conv1 (scalar, packed out) -> conv2 (MFMA)
  //    -> conv3 (scalar)
  k_packw2<<<dim3(60), 256, 0, stream>>>(w2, Bh, Bl);
  k_conv1_pack<<<dim3(576, 8), 192, 0, stream>>>(pooled, w1, b1, C1p);
  k_conv2_mfma<<<dim3(576, 8), 256, 0, stream>>>(C1p, Bh, Bl, b2, C2);
  k_conv4d<10, 1><<<dim3(576, 8), 192, 0, stream>>>(
      C2, (size_t)10 * S4, w3, b3, C3, (size_t)S4);

  // 5) mutual matching #2 -> final output
  k_rowmax<<<dim3(8 * 576), 64, 0, stream>>>(C3, amax2);
  k_colmax<<<dim3(8, 9), 256, 0, stream>>>(C3, bmax2);
  k_mm_apply<<<dim3(10368), 256, 0, stream>>>(C3, amax2, bmax2, out);
}

// Round 2
// 1059.650 us; speedup vs baseline: 1.7937x; 1.2508x over previous
//
#include <hip/hip_runtime.h>
#include <hip/hip_bf16.h>
#include <math.h>

#define C_   1024
#define P_   2304      // 48*48
#define S4   331776    // 24^4

typedef __attribute__((ext_vector_type(8))) short short8;
typedef __attribute__((ext_vector_type(4))) float f32x4;
typedef __attribute__((ext_vector_type(4))) unsigned int u32x4;

__device__ inline unsigned short f2bf(float v) {
  unsigned u = __builtin_bit_cast(unsigned, v);
  u += 0x7fffu + ((u >> 16) & 1u);          // RNE
  return (unsigned short)(u >> 16);
}
__device__ inline float bf2f(unsigned short h) {
  unsigned u = ((unsigned)h) << 16;
  return __builtin_bit_cast(float, u);
}

// async global->LDS DMA, 16B per lane; LDS dest = wave-uniform base + lane*16
__device__ inline void async16(const void* g, void* l) {
  __builtin_amdgcn_global_load_lds(
      (const __attribute__((address_space(1))) unsigned int*)g,
      (__attribute__((address_space(3))) unsigned int*)l, 16, 0, 0);
}

// ---------------- K1: transpose + bf16 hi/lo split + sumsq partials --------
__global__ __launch_bounds__(256) void k_prep(
    const float* __restrict__ fA, const float* __restrict__ fB,
    unsigned short* __restrict__ TAhi, unsigned short* __restrict__ TAlo,
    unsigned short* __restrict__ TBhi, unsigned short* __restrict__ TBlo,
    float* __restrict__ part) {
  __shared__ float ld[64 * 65];
  __shared__ float pslds[512];
  const int c0 = blockIdx.x * 64, p0 = blockIdx.y * 64;
  const int fb = blockIdx.z, f = fb >> 3, b = fb & 7;
  const float* src = (f ? fB : fA) + (size_t)b * C_ * P_;
  unsigned short* Thi = (f ? TBhi : TAhi) + (size_t)b * P_ * C_;
  unsigned short* Tlo = (f ? TBlo : TAlo) + (size_t)b * P_ * C_;
  const int t = threadIdx.x;
#pragma unroll
  for (int e = 0; e < 4; ++e) {
    int cid = t + e * 256;
    int r = cid >> 4, ch = cid & 15;
    float4 v = *(const float4*)&src[(size_t)(c0 + r) * P_ + p0 + ch * 4];
    ld[r * 65 + ch * 4 + 0] = v.x;
    ld[r * 65 + ch * 4 + 1] = v.y;
    ld[r * 65 + ch * 4 + 2] = v.z;
    ld[r * 65 + ch * 4 + 3] = v.w;
  }
  __syncthreads();
#pragma unroll
  for (int e = 0; e < 2; ++e) {
    int ocid = t + e * 256;
    int pl = ocid >> 3, c8 = ocid & 7;
    unsigned short hi[8], lo[8];
    float sq = 0.f;
#pragma unroll
    for (int s = 0; s < 8; ++s) {
      float v = ld[(c8 * 8 + s) * 65 + pl];
      unsigned short h = f2bf(v);
      float rem = v - bf2f(h);
      hi[s] = h; lo[s] = f2bf(rem);
      sq = fmaf(v, v, sq);
    }
    size_t go = (size_t)(p0 + pl) * C_ + c0 + c8 * 8;
    *(uint4*)&Thi[go] = *(uint4*)hi;
    *(uint4*)&Tlo[go] = *(uint4*)lo;
    pslds[ocid] = sq;
  }
  __syncthreads();
  if (t < 64) {
    float s = 0.f;
#pragma unroll
    for (int c8 = 0; c8 < 8; ++c8) s += pslds[t * 8 + c8];
    part[((size_t)fb * 16 + blockIdx.x) * P_ + p0 + t] = s;
  }
}

// ---------------- K2: finalize inverse norms -------------------------------
__global__ void k_invnorm(const float* __restrict__ part, float* __restrict__ inv) {
  int p = blockIdx.x * 256 + threadIdx.x;
  int fb = blockIdx.y;
  float s = 1e-6f;
  for (int ct = 0; ct < 16; ++ct) s += part[((size_t)fb * 16 + ct) * P_ + p];
  inv[(size_t)fb * P_ + p] = 1.0f / sqrtf(s);
}

// ---------------- K3: bf16x3 MFMA correlation + relu/norm/4D-maxpool -------
__global__ __launch_bounds__(256, 3) void k_corr_mfma(
    const unsigned short* __restrict__ TAhi_, const unsigned short* __restrict__ TAlo_,
    const unsigned short* __restrict__ TBhi_, const unsigned short* __restrict__ TBlo_,
    const float* __restrict__ invn, float* __restrict__ pooled) {
  __shared__ __align__(16) char lds_raw[37248];
  unsigned short* stage = (unsigned short*)lds_raw;
  float* epi = (float*)lds_raw;

  const int b = blockIdx.y;
  const size_t tb = (size_t)b * P_ * C_;
  const unsigned short* TAhi = TAhi_ + tb;
  const unsigned short* TAlo = TAlo_ + tb;
  const unsigned short* TBhi = TBhi_ + tb;
  const unsigned short* TBlo = TBlo_ + tb;
  float* out = pooled + (size_t)b * S4;

  const int g = blockIdx.x;
  const int xcd = g & 7, idx = g >> 3;
  const int ti = (xcd & 3) * 6 + idx % 6;
  const int tj = (xcd >> 2) * 12 + idx / 6;
  const int p0 = ti * 96, q0 = tj * 96;
  const int t = threadIdx.x;
  const int lane = t & 63, w = t >> 6;
  const int wr = w >> 1, wc = w & 1;
  const int m15 = lane & 15, q4 = lane >> 4;
  const int koff = q4 * 8;

  f32x4 acc[3][3];
#pragma unroll
  for (int a = 0; a < 3; ++a)
#pragma unroll
    for (int c = 0; c < 3; ++c) acc[a][c] = (f32x4){0.f, 0.f, 0.f, 0.f};

  const unsigned short* gld[8];
  int ldsb[8];
#pragma unroll
  for (int e = 0; e < 8; ++e) {
    int chunk = (w * 8 + e) * 64 + lane;
    int arr = chunk / 480;
    int rem = chunk - arr * 480;
    int row = rem / 5, kc = rem - row * 5;
    bool dum = (arr >= 4) || (kc == 4);
    if (arr >= 4) { arr = 0; row = 0; }
    const unsigned short* base = (arr == 0) ? TAhi : (arr == 1) ? TAlo
                               : (arr == 2) ? TBhi : TBlo;
    int pb = (arr < 2) ? p0 : q0;
    gld[e] = base + (size_t)(pb + row) * C_ + (dum ? 0 : kc * 8);
    ldsb[e] = (w * 8 + e) * 1024;
  }

  for (int kt = 0; kt < C_; kt += 32) {
    __syncthreads();
#pragma unroll
    for (int e = 0; e < 8; ++e)
      async16(gld[e] + kt, lds_raw + ldsb[e]);
    asm volatile("s_waitcnt vmcnt(0)" ::: "memory");
    __syncthreads();

    const unsigned short* Ah = stage;
    const unsigned short* Al = stage + 3840;
    const unsigned short* Bh = stage + 7680;
    const unsigned short* Bl = stage + 11520;
    short8 ah[3], al[3], bh[3], bl[3];
#pragma unroll
    for (int a = 0; a < 3; ++a) {
      int row = wr * 48 + a * 16 + m15;
      ah[a] = *(const short8*)&Ah[row * 40 + koff];
      al[a] = *(const short8*)&Al[row * 40 + koff];
    }
#pragma unroll
    for (int c = 0; c < 3; ++c) {
      int row = wc * 48 + c * 16 + m15;
      bh[c] = *(const short8*)&Bh[row * 40 + koff];
      bl[c] = *(const short8*)&Bl[row * 40 + koff];
    }
#pragma unroll
    for (int a = 0; a < 3; ++a)
#pragma unroll
      for (int c = 0; c < 3; ++c)
        acc[a][c] = __builtin_amdgcn_mfma_f32_16x16x32_bf16(ah[a], bh[c], acc[a][c], 0, 0, 0);
#pragma unroll
    for (int a = 0; a < 3; ++a)
#pragma unroll
      for (int c = 0; c < 3; ++c)
        acc[a][c] = __builtin_amdgcn_mfma_f32_16x16x32_bf16(ah[a], bl[c], acc[a][c], 0, 0, 0);
#pragma unroll
    for (int a = 0; a < 3; ++a)
#pragma unroll
      for (int c = 0; c < 3; ++c)
        acc[a][c] = __builtin_amdgcn_mfma_f32_16x16x32_bf16(al[a], bh[c], acc[a][c], 0, 0, 0);
  }
  __syncthreads();

  const float* invA = invn + (size_t)b * P_;
  const float* invB = invn + (size_t)(8 + b) * P_;
  float ib[3];
#pragma unroll
  for (int c = 0; c < 3; ++c) ib[c] = invB[q0 + wc * 48 + c * 16 + m15];
#pragma unroll
  for (int a = 0; a < 3; ++a) {
#pragma unroll
    for (int reg = 0; reg < 4; ++reg) {
      int pl = wr * 48 + a * 16 + q4 * 4 + reg;
      float ia = invA[p0 + pl];
#pragma unroll
      for (int c = 0; c < 3; ++c) {
        int ql = wc * 48 + c * 16 + m15;
        epi[pl * 97 + ql] = acc[a][c][reg] * ia * ib[c];
      }
    }
  }
  __syncthreads();

  for (int idx2 = t; idx2 < 576; idx2 += 256) {
    int j = idx2 / 24, l = idx2 % 24;
    float m = -1e30f;
#pragma unroll
    for (int dh = 0; dh < 2; ++dh)
#pragma unroll
      for (int dw = 0; dw < 2; ++dw) {
        int row = dh * 48 + 2 * j + dw;
#pragma unroll
        for (int d2 = 0; d2 < 2; ++d2)
#pragma unroll
          for (int dw2 = 0; dw2 < 2; ++dw2)
            m = fmaxf(m, epi[row * 97 + d2 * 48 + 2 * l + dw2]);
      }
    float r = fmaxf(m, 0.f);
    float v = r / sqrtf(r * r + 1e-6f);
    out[(size_t)(ti * 24 + j) * 576 + tj * 24 + l] = v;
  }
}

// ---------------- K4a: row max (over kl, per ij) ---------------------------
__global__ void k_rowmax(const float* __restrict__ x, float* __restrict__ amax) {
  int row = blockIdx.x;
  const float* r = x + (size_t)row * 576;
  float m = -1e30f;
  for (int e = threadIdx.x; e < 576; e += 64) m = fmaxf(m, r[e]);
  for (int off = 32; off > 0; off >>= 1) m = fmaxf(m, __shfl_down(m, off, 64));
  if (threadIdx.x == 0) amax[row] = m;
}

// ---------------- K4b: col max (over ij, per kl) ---------------------------
__global__ void k_colmax(const float* __restrict__ x, float* __restrict__ bmax) {
  __shared__ float pl[4][64];
  int b = blockIdx.x, klc = blockIdx.y * 64;
  int t = threadIdx.x;
  int kl = klc + (t & 63), seg = t >> 6;
  const float* xb = x + (size_t)b * S4;
  float m = -1e30f;
  for (int ij = seg * 144; ij < (seg + 1) * 144; ++ij)
    m = fmaxf(m, xb[(size_t)ij * 576 + kl]);
  pl[seg][t & 63] = m;
  __syncthreads();
  if (t < 64) {
    float r = fmaxf(fmaxf(pl[0][t], pl[1][t]), fmaxf(pl[2][t], pl[3][t]));
    bmax[b * 576 + klc + t] = r;
  }
}

// ---------------- K5: mutual matching elementwise --------------------------
__global__ void k_mm_apply(const float* __restrict__ x,
                           const float* __restrict__ amax,
                           const float* __restrict__ bmax,
                           float* __restrict__ y) {
  int i = blockIdx.x * 256 + threadIdx.x;
  int b = i / S4, r = i % S4;
  int ij = r / 576, kl = r % 576;
  float c = x[i];
  y[i] = c * (c / (amax[b * 576 + ij] + 1e-5f)) * (c / (bmax[b * 576 + kl] + 1e-5f));
}

// ---------------- K7: conv1 (CIN=1, COUT=10) -> packed halo layout ---------
// C1p[b][ij slab][pos 26*26][ci 10] dwords; pos=(k'+1)*26+(l'+1); value =
// (bf16_hi<<16)|bf16_lo of relu(conv1+b1). Halo rows/cols and pad [6760,6912)
// zeroed (pad IS read by conv2's K=32 window overrun -> must be finite).
__global__ __launch_bounds__(192, 4) void k_conv1_pack(
    const float* __restrict__ x, const float* __restrict__ w,
    const float* __restrict__ bias, unsigned int* __restrict__ C1p) {
  __shared__ float tile[9 * 702];
  const float* xb = x + (size_t)S4 * blockIdx.y;
  unsigned int* yb = C1p + ((size_t)blockIdx.y * 576 + blockIdx.x) * 6912;
  const int ij = blockIdx.x;
  const int i = ij / 24, j = ij % 24;
  const int t = threadIdx.x;
  const int k = t >> 3;
  const int l0 = (t & 7) * 3;

  if (t < 152) yb[6760 + t] = 0u;
  if (t < 100) {
    int kk, ll;
    if (t < 26)      { kk = 0;          ll = t; }
    else if (t < 52) { kk = 25;         ll = t - 26; }
    else if (t < 76) { kk = t - 52 + 1; ll = 0; }
    else             { kk = t - 76 + 1; ll = 25; }
    unsigned int* p = yb + (kk * 26 + ll) * 10;
#pragma unroll
    for (int q = 0; q < 10; ++q) p[q] = 0u;
  }

  int soff[4]; bool eok[4], klok[4]; int eidx[4];
#pragma unroll
  for (int q = 0; q < 4; ++q) {
    int e = t + q * 192;
    eidx[q] = e; eok[q] = (e < 702);
    int row = e / 27, col = e % 27;
    klok[q] = (row >= 1 && row < 25 && col >= 1 && col < 25);
    soff[q] = (row - 1) * 24 + (col - 1);
  }

  float acc[10][3];
#pragma unroll
  for (int co = 0; co < 10; ++co)
#pragma unroll
    for (int oo = 0; oo < 3; ++oo) acc[co][oo] = 0.f;

#pragma unroll
  for (int pln = 0; pln < 9; ++pln) {
    int ii = i + pln / 3 - 1, jj = j + pln % 3 - 1;
    const bool slab_ok = (ii >= 0 && ii < 24 && jj >= 0 && jj < 24);
    const float* src = xb + (size_t)(ii * 24 + jj) * 576;
#pragma unroll
    for (int q = 0; q < 4; ++q) {
      if (eok[q]) {
        float v = 0.f;
        if (slab_ok && klok[q]) v = src[soff[q]];
        tile[pln * 702 + eidx[q]] = v;
      }
    }
  }
  __syncthreads();
#pragma unroll
  for (int pln = 0; pln < 9; ++pln) {
    const float* base = &tile[pln * 702 + k * 27 + l0];
#pragma unroll
    for (int dk = 0; dk < 3; ++dk) {
      float c0 = base[dk * 27 + 0], c1 = base[dk * 27 + 1],
            c2 = base[dk * 27 + 2], c3 = base[dk * 27 + 3],
            c4 = base[dk * 27 + 4];
#pragma unroll
      for (int co = 0; co < 10; ++co) {
        const float* wr = w + (size_t)co * 81 + pln * 9 + dk * 3;
        float w0 = wr[0], w1 = wr[1], w2v = wr[2];
        acc[co][0] = fmaf(w0, c0, acc[co][0]);
        acc[co][0] = fmaf(w1, c1, acc[co][0]);
        acc[co][0] = fmaf(w2v, c2, acc[co][0]);
        acc[co][1] = fmaf(w0, c1, acc[co][1]);
        acc[co][1] = fmaf(w1, c2, acc[co][1]);
        acc[co][1] = fmaf(w2v, c3, acc[co][1]);
        acc[co][2] = fmaf(w0, c2, acc[co][2]);
        acc[co][2] = fmaf(w1, c3, acc[co][2]);
        acc[co][2] = fmaf(w2v, c4, acc[co][2]);
      }
    }
  }
#pragma unroll
  for (int oo = 0; oo < 3; ++oo) {
    unsigned int* baseo = yb + ((k + 1) * 26 + (l0 + oo + 1)) * 10;
#pragma unroll
    for (int co = 0; co < 10; ++co) {
      float v = fmaxf(acc[co][oo] + bias[co], 0.f);
      unsigned short hi = f2bf(v);
      unsigned short lo = f2bf(v - bf2f(hi));
      baseo[co] = ((unsigned)hi << 16) | (unsigned)lo;
    }
  }
}

// ---------------- K8: pack conv2 weights into B fragments ------------------
// Bh/Bl [30 taps][16 co][32 kappa]; kappa = dl*10+ci (30 used, 2 zero);
// taps 0..26 = (di,dj,dk), taps 27..29 = all-zero (for out-of-range slabs).
__global__ void k_packw2(const float* __restrict__ w2,
                         unsigned short* __restrict__ Bh,
                         unsigned short* __restrict__ Bl) {
  int idx = blockIdx.x * 256 + threadIdx.x;
  if (idx >= 15360) return;
  int tap = idx >> 9;
  int n = (idx >> 5) & 15;
  int kap = idx & 31;
  float v = 0.f;
  if (tap < 27 && n < 10 && kap < 30) {
    int ci = kap % 10, dl = kap / 10;
    v = w2[(size_t)(n * 10 + ci) * 81 + tap * 3 + dl];
  }
  unsigned short hi = f2bf(v);
  unsigned short lo = f2bf(v - bf2f(hi));
  Bh[idx] = hi; Bl[idx] = lo;
}

// ---------------- K8b: pack conv3 weights into B fragments -----------------
// Bh/Bl [9 slabs][16 n][32 kappa]; n = dk (3 used, 13 zero); kappa = dl*10+ci
// (30 used, 2 zero). w3 layout: [1][10 ci][3 di][3 dj][3 dk][3 dl].
__global__ void k_packw3(const float* __restrict__ w3,
                         unsigned short* __restrict__ Bh,
                         unsigned short* __restrict__ Bl) {
  int idx = blockIdx.x * 256 + threadIdx.x;
  if (idx >= 4608) return;
  int s = idx >> 9;            // slab (di,dj) 0..8
  int n = (idx >> 5) & 15;     // dk
  int kap = idx & 31;
  float v = 0.f;
  if (n < 3 && kap < 30) {
    int ci = kap % 10, dl = kap / 10;
    v = w3[(size_t)ci * 81 + s * 9 + n * 3 + dl];
  }
  unsigned short hi = f2bf(v);
  unsigned short lo = f2bf(v - bf2f(hi));
  Bh[idx] = hi; Bl[idx] = lo;
}

// ---------------- K9: conv2 (10->10) via MFMA, tap-decomposed GEMM ---------
// One block per (b, ij). M = 576 outputs, N = 16 (10 co), K = 32 window =
// 3 dl-shifts x 10 ci. 9 slabs x 3 dk taps, bf16x3: AhBh + AhBl + AlBh.
// Slab loop fully unrolled; per-iter B locals kill the bhc=bhn copies that
// forced a compiler vmcnt(0) at each loop tail. vmcnt(13) = LOADB(s)[6] +
// STAGE(s+1)[7] newest outstanding; drains STAGE(s). Epilogue writes the
// packed halo layout C2p (same as C1p) for conv3's MFMA consumption.
__global__ __launch_bounds__(256, 2) void k_conv2_mfma(
    const unsigned int* __restrict__ C1p,
    const unsigned short* __restrict__ Bh, const unsigned short* __restrict__ Bl,
    const float* __restrict__ bias, unsigned int* __restrict__ C2p) {
  __shared__ __align__(16) unsigned int lds[2 * 7168];
  const int b = blockIdx.y, ij = blockIdx.x;
  const int i = ij / 24, j = ij % 24;
  const int t = threadIdx.x, lane = t & 63, w = t >> 6;
  const int m15 = lane & 15, q4 = lane >> 4;

  // zero halo border + pad of own output slab (block-owned, disjoint addrs)
  unsigned int* yb = C2p + ((size_t)b * 576 + ij) * 6912;
  if (t < 152) yb[6760 + t] = 0u;
  if (t < 100) {
    int kk, ll;
    if (t < 26)      { kk = 0;          ll = t; }
    else if (t < 52) { kk = 25;         ll = t - 26; }
    else if (t < 76) { kk = t - 52 + 1; ll = 0; }
    else             { kk = t - 76 + 1; ll = 25; }
    unsigned int* p = yb + (kk * 26 + ll) * 10;
#pragma unroll
    for (int q = 0; q < 10; ++q) p[q] = 0u;
  }

  int rowb[9];
#pragma unroll
  for (int mi = 0; mi < 9; ++mi) {
    int kl = (w * 9 + mi) * 16 + m15;
    int kk = kl / 24, ll = kl % 24;
    rowb[mi] = ((kk + 1) * 26 + ll) * 10;
  }

  const unsigned int* sptr[9]; int tb[9];
#pragma unroll
  for (int s = 0; s < 9; ++s) {
    int di = s / 3 - 1, dj = s % 3 - 1;
    int ii = i + di, jj = j + dj;
    bool v = ((unsigned)ii < 24u) && ((unsigned)jj < 24u);
    sptr[s] = C1p + ((size_t)b * 576 + (size_t)(v ? (ii * 24 + jj) : ij)) * 6912;
    tb[s] = v ? s * 3 : 27;   // invalid slab -> zero-weight taps 27..29
  }

  auto STAGE = [&](const unsigned int* sp, int par) {
#pragma unroll
    for (int r = 0; r < 7; ++r) {
      const int g = w * 7 + r;                         // 0..27
      const unsigned int* gp = sp + (g < 27 ? g * 256 : 0) + lane * 4;
      async16(gp, (char*)lds + par * 28672 + g * 1024);
    }
  };

  f32x4 acc[9];
#pragma unroll
  for (int mi = 0; mi < 9; ++mi) acc[mi] = (f32x4){0.f, 0.f, 0.f, 0.f};

  STAGE(sptr[0], 0);

#pragma unroll
  for (int s = 0; s < 9; ++s) {
    const int par = s & 1;
    short8 bh_[3], bl_[3];
#pragma unroll
    for (int dk = 0; dk < 3; ++dk) {
      size_t o = (size_t)((tb[s] + dk) * 16 + m15) * 32 + (size_t)q4 * 8;
      bh_[dk] = *(const short8*)(Bh + o);
      bl_[dk] = *(const short8*)(Bl + o);
    }
    if (s < 8) {
      STAGE(sptr[s + 1], par ^ 1);
      asm volatile("s_waitcnt vmcnt(13)" ::: "memory");
    } else {
      asm volatile("s_waitcnt vmcnt(6)" ::: "memory");
    }
    __builtin_amdgcn_s_barrier();
    __builtin_amdgcn_sched_barrier(0);

    const unsigned int* buf = lds + par * 7168;
#pragma unroll
    for (int dk = 0; dk < 3; ++dk) {
#pragma unroll
      for (int mi = 0; mi < 9; ++mi) {
        const uint2* p = (const uint2*)(buf + (rowb[mi] + (dk - 1) * 260 + q4 * 8));
        uint2 d0 = p[0], d1 = p[1], d2 = p[2], d3 = p[3];
        u32x4 hd, lv;
        hd.x = __builtin_amdgcn_perm(d0.y, d0.x, 0x07060302u);
        hd.y = __builtin_amdgcn_perm(d1.y, d1.x, 0x07060302u);
        hd.z = __builtin_amdgcn_perm(d2.y, d2.x, 0x07060302u);
        hd.w = __builtin_amdgcn_perm(d3.y, d3.x, 0x07060302u);
        lv.x = __builtin_amdgcn_perm(d0.y, d0.x, 0x05040100u);
        lv.y = __builtin_amdgcn_perm(d1.y, d1.x, 0x05040100u);
        lv.z = __builtin_amdgcn_perm(d2.y, d2.x, 0x05040100u);
        lv.w = __builtin_amdgcn_perm(d3.y, d3.x, 0x05040100u);
        short8 ah = __builtin_bit_cast(short8, hd);
        short8 al = __builtin_bit_cast(short8, lv);
        acc[mi] = __builtin_amdgcn_mfma_f32_16x16x32_bf16(ah, bh_[dk], acc[mi], 0, 0, 0);
        acc[mi] = __builtin_amdgcn_mfma_f32_16x16x32_bf16(ah, bl_[dk], acc[mi], 0, 0, 0);
        acc[mi] = __builtin_amdgcn_mfma_f32_16x16x32_bf16(al, bh_[dk], acc[mi], 0, 0, 0);
      }
    }
    __builtin_amdgcn_sched_barrier(0);
    __builtin_amdgcn_s_barrier();
  }

  if (m15 < 10) {
    const float bv = bias[m15];
#pragma unroll
    for (int mi = 0; mi < 9; ++mi) {
#pragma unroll
      for (int reg = 0; reg < 4; ++reg) {
        int kl = (w * 9 + mi) * 16 + q4 * 4 + reg;
        int kk = kl / 24 + 1, ll = kl % 24 + 1;
        float v = fmaxf(acc[mi][reg] + bv, 0.f);
        unsigned short hi = f2bf(v);
        unsigned short lo = f2bf(v - bf2f(hi));
        yb[(kk * 26 + ll) * 10 + m15] = ((unsigned)hi << 16) | (unsigned)lo;
      }
    }
  }
}

// ---------------- K10: conv3 (10->1) via MFMA, dk-in-N two-stage -----------
// Stage 1: u_dk[k'][l] = sum_{slabs,dl,ci} w3 * x  as GEMM: M = 624 padded
// positions (k' in 0..25, l in 0..23), N = 3 (dk in cols 0..2 of 16),
// K = 32 window (dl*10+ci, 30 used), accumulated over 9 slabs.
// Stage 2: out[k][l] = relu(b3 + sum_dk u_dk[k+dk][l]) via LDS.
// B operand is 18 KB total -> fully preloaded to registers (72 VGPR); slab
// loop fully unrolled; vmcnt(7) keeps only next-slab DMA outstanding.
__global__ __launch_bounds__(256, 2) void k_conv3_mfma(
    const unsigned int* __restrict__ C2p,
    const unsigned short* __restrict__ Bh, const unsigned short* __restrict__ Bl,
    const float* __restrict__ bias, float* __restrict__ C3) {
  __shared__ __align__(16) unsigned int lds[2 * 7168];
  const int b = blockIdx.y, ij = blockIdx.x;
  const int i = ij / 24, j = ij % 24;
  const int t = threadIdx.x, lane = t & 63, w = t >> 6;
  const int m15 = lane & 15, q4 = lane >> 4;

  // per-lane A row bases: m = kp*24 + l (kp = padded row 0..25); tile 39's
  // tail rows (m >= 624) clamp to 0 (results discarded in stage 2).
  int rowb[10];
#pragma unroll
  for (int mi = 0; mi < 10; ++mi) {
    int m = (w * 10 + mi) * 16 + m15;
    int kp = m / 24, l = m % 24;
    rowb[mi] = (m < 624) ? (kp * 26 + l) * 10 : 0;
  }

  bool sval[9];
  const unsigned int* sptr[9];
#pragma unroll
  for (int s = 0; s < 9; ++s) {
    int di = s / 3 - 1, dj = s % 3 - 1;
    int ii = i + di, jj = j + dj;
    bool v = ((unsigned)ii < 24u) && ((unsigned)jj < 24u);
    sval[s] = v;
    sptr[s] = C2p + ((size_t)b * 576 + (size_t)(v ? (ii * 24 + jj) : ij)) * 6912;
  }

  // preload all 9 slabs' B fragments (9 x 2 x 4 VGPR = 72 VGPR)
  short8 BHk[9], BLk[9];
#pragma unroll
  for (int s = 0; s < 9; ++s) {
    size_t o = (size_t)(s * 16 + m15) * 32 + (size_t)q4 * 8;
    BHk[s] = *(const short8*)(Bh + o);
    BLk[s] = *(const short8*)(Bl + o);
  }

  auto STAGE = [&](const unsigned int* sp, int par) {
#pragma unroll
    for (int r = 0; r < 7; ++r) {
      const int g = w * 7 + r;                         // 0..27
      const unsigned int* gp = sp + (g < 27 ? g * 256 : 0) + lane * 4;
      async16(gp, (char*)lds + par * 28672 + g * 1024);
    }
  };

  f32x4 acc[10];
#pragma unroll
  for (int mi = 0; mi < 10; ++mi) acc[mi] = (f32x4){0.f, 0.f, 0.f, 0.f};

  STAGE(sptr[0], 0);

#pragma unroll
  for (int s = 0; s < 9; ++s) {
    const int par = s & 1;
    if (s < 8) {
      STAGE(sptr[s + 1], par ^ 1);
      asm volatile("s_waitcnt vmcnt(7)" ::: "memory");
    } else {
      asm volatile("s_waitcnt vmcnt(0)" ::: "memory");
    }
    __builtin_amdgcn_s_barrier();
    __builtin_amdgcn_sched_barrier(0);
    if (sval[s]) {                       // block-uniform branch
      const unsigned int* buf = lds + par * 7168;
#pragma unroll
      for (int mi = 0; mi < 10; ++mi) {
        const uint2* p = (const uint2*)(buf + rowb[mi] + q4 * 8);
        uint2 d0 = p[0], d1 = p[1], d2 = p[2], d3 = p[3];
        u32x4 hd, lv;
        hd.x = __builtin_amdgcn_perm(d0.y, d0.x, 0x07060302u);
        hd.y = __builtin_amdgcn_perm(d1.y, d1.x, 0x07060302u);
        hd.z = __builtin_amdgcn_perm(d2.y, d2.x, 0x07060302u);
        hd.w = __builtin_amdgcn_perm(d3.y, d3.x, 0x07060302u);
        lv.x = __builtin_amdgcn_perm(d0.y, d0.x, 0x05040100u);
        lv.y = __builtin_amdgcn_perm(d1.y, d1.x, 0x05040100u);
        lv.z = __builtin_amdgcn_perm(d2.y, d2.x, 0x05040100u);
        lv.w = __builtin_amdgcn_perm(d3.y, d3.x, 0x05040100u);
        short8 ah = __builtin_bit_cast(short8, hd);
        short8 al = __builtin_bit_cast(short8, lv);
        acc[mi] = __builtin_amdgcn_mfma_f32_16x16x32_bf16(ah, BHk[s], acc[mi], 0, 0, 0);
        acc[mi] = __builtin_amdgcn_mfma_f32_16x16x32_bf16(ah, BLk[s], acc[mi], 0, 0, 0);
        acc[mi] = __builtin_amdgcn_mfma_f32_16x16x32_bf16(al, BHk[s], acc[mi], 0, 0, 0);
      }
    }
    __builtin_amdgcn_sched_barrier(0);
    __builtin_amdgcn_s_barrier();
  }

  // stage 2: u[m][dk] in LDS (post-loop barrier guarantees all reads done)
  float* u = (float*)lds;                // 640*4 floats = 10240 B
  if (m15 < 3) {
#pragma unroll
    for (int mi = 0; mi < 10; ++mi)
#pragma unroll
      for (int reg = 0; reg < 4; ++reg) {
        int m = (w * 10 + mi) * 16 + q4 * 4 + reg;
        u[m * 4 + m15] = acc[mi][reg];
      }
  }
  __syncthreads();
  const float bv = bias[0];
  float* outp = C3 + (size_t)b * S4 + (size_t)ij * 576;
  for (int idx = t; idx < 576; idx += 256) {
    int k = idx / 24, l = idx % 24;
    float sum = u[((k + 0) * 24 + l) * 4 + 0]
              + u[((k + 1) * 24 + l) * 4 + 1]
              + u[((k + 2) * 24 + l) * 4 + 2];
    outp[idx] = fmaxf(sum + bv, 0.f);
  }
}

// ---------------------------------------------------------------------------
extern "C" void kernel_launch(void* const* d_in, const int* in_sizes, int n_in,
                              void* d_out, int out_size, void* d_ws, size_t ws_size,
                              hipStream_t stream) {
  const float* fA = (const float*)d_in[0];
  const float* fB = (const float*)d_in[1];
  const float* w1 = (const float*)d_in[2];
  const float* b1 = (const float*)d_in[3];
  const float* w2 = (const float*)d_in[4];
  const float* b2 = (const float*)d_in[5];
  const float* w3 = (const float*)d_in[6];
  const float* b3 = (const float*)d_in[7];
  float* out = (float*)d_out;
  float* ws = (float*)d_ws;
  (void)in_sizes; (void)n_in; (void)out_size; (void)ws_size;

  // --- workspace layout (floats/dwords), peak 63,720,960 fl = 254.9 MB ---
  // lifetimes: T arrays [0,37.75M) die after corr; C1p [0,31.85M) lives
  // conv1_pack..conv2; C2p [31.85M,63.70M) lives conv2..conv3 (overlays
  // pooled/part/invn/amax1/bmax1, all dead before conv2 writes); C3 [0,2.65M)
  // overlays dead C1p; B-frag packs at tail (alive during conv2/conv3).
  unsigned int* C1p  = (unsigned int*)ws;            // 31,850,496 dw
  unsigned int* C2p  = (unsigned int*)(ws + 31850496); // 31,850,496 dw
  unsigned short* TAhi = (unsigned short*)ws;        // 4 x 18,874,368 shorts
  unsigned short* TAlo = TAhi + (size_t)8 * P_ * C_;
  unsigned short* TBhi = TAlo + (size_t)8 * P_ * C_;
  unsigned short* TBlo = TBhi + (size_t)8 * P_ * C_; // ends at fl 37,748,736
  float* pooled = ws + 37748736;                     // 2,654,208
  float* part   = ws + 40402944;                     // 589,824
  float* invn   = ws + 40992768;                     // 36,864
  float* amax1  = ws + 41029632;                     // 4,608
  float* bmax1  = ws + 41034240;                     // 4,608
  float* C3     = ws + 0;                            // 2,654,208 (over dead C1p)
  float* amax2  = ws + 2654208;
  float* bmax2  = ws + 2658816;
  unsigned short* Bh2 = (unsigned short*)(ws + 63700992);  // 15,360 shorts
  unsigned short* Bl2 = Bh2 + 15360;
  unsigned short* Bh3 = Bl2 + 15360;                       // 4,608 shorts
  unsigned short* Bl3 = Bh3 + 4608;

  // 1+2) transpose/split + norms + MFMA correlation
  k_prep<<<dim3(16, 36, 16), 256, 0, stream>>>(fA, fB, TAhi, TAlo, TBhi, TBlo, part);
  k_invnorm<<<dim3(9, 16), 256, 0, stream>>>(part, invn);
  k_corr_mfma<<<dim3(576, 8), 256, 0, stream>>>(TAhi, TAlo, TBhi, TBlo, invn, pooled);

  // 3) mutual matching #1 (in place)
  k_rowmax<<<dim3(8 * 576), 64, 0, stream>>>(pooled, amax1);
  k_colmax<<<dim3(8, 9), 256, 0, stream>>>(pooled, bmax1);
  k_mm_apply<<<dim3(10368), 256, 0, stream>>>(pooled, amax1, bmax1, pooled);

  // 4) neighbourhood consensus: conv1 (scalar, packed out) -> conv2 (MFMA,
  //    packed halo out) -> conv3 (MFMA, dk-in-N)
  k_packw2<<<dim3(60), 256, 0, stream>>>(w2, Bh2, Bl2);
  k_packw3<<<dim3(18), 256, 0, stream>>>(w3, Bh3, Bl3);
  k_conv1_pack<<<dim3(576, 8), 192, 0, stream>>>(pooled, w1, b1, C1p);
  k_conv2_mfma<<<dim3(576, 8), 256, 0, stream>>>(C1p, Bh2, Bl2, b2, C2p);
  k_conv3_mfma<<<dim3(576, 8), 256, 0, stream>>>(C2p, Bh3, Bl3, b3, C3);

  // 5) mutual matching #2 -> final output
  k_rowmax<<<dim3(8 * 576), 64, 0, stream>>>(C3, amax2);
  k_colmax<<<dim3(8, 9), 256, 0, stream>>>(C3, bmax2);
  k_mm_apply<<<dim3(10368), 256, 0, stream>>>(C3, amax2, bmax2, out);
}